// Round 16
// baseline (807.521 us; speedup 1.0000x reference)
//
#include <hip/hip_runtime.h>
#include <hip/hip_bf16.h>

// VectorQuantize: argmin_k ||x - e_k||^2 then gather values[k].
// R16 = R15 (i8 256x256 tile, 16-wave single block/CU, 571-595 us family)
// with ONE change: BK=128 -> NSTEP=4. R1-R15 ledger shows wall ~= 20-24k
// cycles per SEQUENTIAL barrier-step, nearly independent of bytes staged
// (16-64 KB/step all cost the same); every recent design had 64 sequential
// steps (8 rounds x 8 steps) ~= 590 us. Halving step count to 32 is the
// discriminating test: fixed-cost model predicts ~2x faster; byte-service
// model predicts no change (-> declare roofline).
// Quantization/rescue unchanged (R12-proven): per-row symmetric i8, score =
// e_sq - 2*sx*se*idot, per-wave top-2 sortable keys -> global top-4 ->
// exact f32 rescore (np tie semantics) -> gather values[best].
//
// Pack layout (granule = 16 i8): P[tile256][k16 0..31][row 0..255][16].
// K-step t (BK=128) stages k16 = 8t..8t+7: 2048 granules (32 KB) each of
// A and B; granule f = k16l*256+row identical in global and LDS.

#define D      512
#define M      16384
#define NCODE  8192
#define NSTEP  4           // K=512 / BK=128
#define TILEB  131072      // bytes per 256-row i8 tile (256*512)

typedef int   i32x4 __attribute__((ext_vector_type(4)));
typedef float f32x4 __attribute__((ext_vector_type(4)));

#define KMAX 0xFFFFFFFFFFFFFFFFull

__device__ __forceinline__ void gload16(const void* g, void* l) {
  __builtin_amdgcn_global_load_lds(
      (const __attribute__((address_space(1))) void*)g,
      (__attribute__((address_space(3))) void*)l, 16, 0, 0);
}

__device__ __forceinline__ unsigned long long score_key(float sc, int code) {
  unsigned int u = __float_as_uint(sc);
  unsigned int su = u ^ ((unsigned int)((int)u >> 31) | 0x80000000u);
  return ((unsigned long long)su << 32) | (unsigned int)code;
}

__device__ __forceinline__ void kins2(unsigned long long k,
                                      unsigned long long& k1, unsigned long long& k2) {
  if (k < k1) { k2 = k1; k1 = k; }
  else if (k < k2) { k2 = k; }
}

__device__ __forceinline__ void kins4(unsigned long long k,
    unsigned long long& k0, unsigned long long& k1,
    unsigned long long& k2, unsigned long long& k3) {
  if (k < k0)      { k3 = k2; k2 = k1; k1 = k0; k0 = k; }
  else if (k < k1) { k3 = k2; k2 = k1; k1 = k; }
  else if (k < k2) { k3 = k2; k2 = k; }
  else if (k < k3) { k3 = k; }
}

// ---- 1. per-row scales (+ e_sq for codebook) --------------------------------
__global__ __launch_bounds__(256)
void scales_kernel(const float* __restrict__ x, const float* __restrict__ cb,
                   float* __restrict__ qmul_x, float* __restrict__ sval_x,
                   float* __restrict__ qmul_e, float* __restrict__ sval_e,
                   float* __restrict__ e_sq) {
  int gw = (blockIdx.x * 256 + threadIdx.x) >> 6;
  int lane = threadIdx.x & 63;
  bool isx = gw < M;
  int row = isx ? gw : gw - M;
  const float4* s4 = (const float4*)((isx ? x : cb) + (size_t)row * D);
  float ma = 0.f, ss = 0.f;
#pragma unroll
  for (int i = 0; i < 2; ++i) {
    float4 v = s4[lane + i * 64];
    ma = fmaxf(ma, fmaxf(fmaxf(fabsf(v.x), fabsf(v.y)), fmaxf(fabsf(v.z), fabsf(v.w))));
    ss += v.x * v.x + v.y * v.y + v.z * v.z + v.w * v.w;
  }
#pragma unroll
  for (int off = 32; off > 0; off >>= 1) {
    ma = fmaxf(ma, __shfl_down(ma, off, 64));
    ss += __shfl_down(ss, off, 64);
  }
  if (lane == 0) {
    ma = fmaxf(ma, 1e-30f);
    if (isx) { qmul_x[row] = 127.0f / ma; sval_x[row] = ma / 127.0f; }
    else     { qmul_e[row] = 127.0f / ma; sval_e[row] = ma / 127.0f; e_sq[row] = ss; }
  }
}

// ---- 2. f32 -> i8 256-row tile-transposed pack (R12-proven) -----------------
__global__ __launch_bounds__(256)
void prep_i8(const float* __restrict__ src, const float* __restrict__ qmul,
             char* __restrict__ dst) {
  __shared__ char tile[256][80];   // 20 KB, 16B-aligned rows
  const int tid = threadIdx.x;
  const int c = blockIdx.x & 7, t = blockIdx.x >> 3;
  const float* srow = src + (size_t)t * 256 * D;
  char* dbase = dst + (size_t)t * TILEB;

#pragma unroll
  for (int j = 0; j < 4; ++j) {
    int f = tid + j * 256;               // 1024 granules: row = f>>2, k16l = f&3
    int row = f >> 2, k16l = f & 3;
    const float4* p = (const float4*)(srow + (size_t)row * D + c * 64 + k16l * 16);
    float qm = qmul[t * 256 + row];
    union { i32x4 v; signed char b[16]; } pk;
#pragma unroll
    for (int u = 0; u < 4; ++u) {
      float4 v = p[u];
      float vv[4] = {v.x, v.y, v.z, v.w};
#pragma unroll
      for (int e = 0; e < 4; ++e) {
        int q = __float2int_rn(vv[e] * qm);
        q = q > 127 ? 127 : (q < -127 ? -127 : q);
        pk.b[u * 4 + e] = (signed char)q;
      }
    }
    *(i32x4*)&tile[row][k16l * 16] = pk.v;
  }
  __syncthreads();
#pragma unroll
  for (int j = 0; j < 4; ++j) {
    int g = tid + j * 256;               // out granule: row = g&255, k16l = g>>8
    int row = g & 255, k16l = g >> 8;
    i32x4 v = *(const i32x4*)&tile[row][k16l * 16];
    *(i32x4*)(dbase + (((size_t)(c * 4 + k16l) * 256 + row) * 16)) = v;
  }
}

// ---- 3. 256x256-tile BK=128 i8 GEMM, ONE 16-wave block/CU, 4 steps ----------
// 1024 threads = 16 waves (wr, wc in 0..3). Wave tile: 64 rows x 64 codes.
// Swapped mfma_i32_16x16x64_i8(b, a): acc[nc][m][q] -> code = ct*256 + wc*64 +
// nc*16 + lh*4 + q, row = mt*256 + wr*64 + m*16 + lr.
__global__ __launch_bounds__(1024, 4)
void vq_gemm_i8k(const char* __restrict__ Apack, const char* __restrict__ Bpack,
                 const float* __restrict__ e_sq,
                 const float* __restrict__ sval_x, const float* __restrict__ sval_e,
                 ulonglong2* __restrict__ cand2) {
  extern __shared__ char smem[];
  // granule map (16 B): buf*4096 + {A: 0..2047, B: 2048..4095}; 2 bufs = 128 KB

  const int tid = threadIdx.x;
  const int w = tid >> 6, l = tid & 63;
  const int wr = w >> 2, wc = w & 3;
  const int lr = l & 15, lh = l >> 4;

  // XCD-pinned map (R11/R14: ordering perf-neutral; keep L2-friendly).
  const int bid = blockIdx.x;
  const int xcd = bid & 7, idx = bid >> 3;   // 256 blocks per XCD
  const int mt = xcd * 8 + (idx & 7);        // 64 m-tiles
  const int ct = idx >> 3;                   // 32 c-tiles

  const char* Abase = Apack + (size_t)mt * TILEB;
  const char* Bbase = Bpack + (size_t)ct * TILEB;

  i32x4 acc[4][4] = {};

#define STAGE(buf, t)                                                          \
  do {                                                                         \
    _Pragma("unroll")                                                          \
    for (int i = 0; i < 2; ++i) {                                              \
      const int g = tid + i * 1024;                                            \
      gload16(Abase + ((size_t)(t) * 2048 + g) * 16,                           \
              smem + ((size_t)(buf) * 4096 + g) * 16);                         \
      gload16(Bbase + ((size_t)(t) * 2048 + g) * 16,                           \
              smem + ((size_t)(buf) * 4096 + 2048 + g) * 16);                  \
    }                                                                          \
  } while (0)

#define COMPUTE(buf)                                                           \
  do {                                                                         \
    const i32x4* Ag = (const i32x4*)smem + (buf) * 4096;                       \
    const i32x4* Bg = Ag + 2048;                                               \
    _Pragma("unroll")                                                          \
    for (int kk = 0; kk < 2; ++kk) {                                           \
      const int kb = (kk * 4 + lh) * 256;                                      \
      i32x4 a[4], b[4];                                                        \
      _Pragma("unroll")                                                        \
      for (int nc = 0; nc < 4; ++nc) b[nc] = Bg[kb + wc * 64 + nc * 16 + lr];  \
      _Pragma("unroll")                                                        \
      for (int m = 0; m < 4; ++m)   a[m] = Ag[kb + wr * 64 + m * 16 + lr];     \
      _Pragma("unroll")                                                        \
      for (int nc = 0; nc < 4; ++nc)                                           \
        _Pragma("unroll")                                                      \
        for (int m = 0; m < 4; ++m)                                            \
          acc[nc][m] = __builtin_amdgcn_mfma_i32_16x16x64_i8(b[nc], a[m],      \
                                                             acc[nc][m], 0, 0, 0); \
    }                                                                          \
  } while (0)

  STAGE(0, 0);
  __syncthreads();
#pragma unroll 1
  for (int t = 0; t < NSTEP - 1; ++t) {
    const int cur = t & 1;
    STAGE(cur ^ 1, t + 1);       // prefetch issued before compute
    COMPUTE(cur);
    __syncthreads();             // one barrier per step (32 sequential/CU)
  }
  COMPUTE((NSTEP - 1) & 1);
#undef STAGE
#undef COMPUTE

  // ---- epilogue: per-row top-2 keys over this wave's 64-code strip ----
  const int col0 = ct * 256 + wc * 64;
  float es[4][4], sev[4][4], sxv[4];
#pragma unroll
  for (int nc = 0; nc < 4; ++nc) {
    float4 e4 = *(const float4*)&e_sq[col0 + nc * 16 + lh * 4];
    float4 s4 = *(const float4*)&sval_e[col0 + nc * 16 + lh * 4];
    es[nc][0] = e4.x; es[nc][1] = e4.y; es[nc][2] = e4.z; es[nc][3] = e4.w;
    sev[nc][0] = s4.x; sev[nc][1] = s4.y; sev[nc][2] = s4.z; sev[nc][3] = s4.w;
  }
#pragma unroll
  for (int m = 0; m < 4; ++m)
    sxv[m] = sval_x[mt * 256 + wr * 64 + m * 16 + lr];

#pragma unroll
  for (int m = 0; m < 4; ++m) {
    unsigned long long k1 = KMAX, k2 = KMAX;
    const float sx2 = 2.0f * sxv[m];
#pragma unroll
    for (int nc = 0; nc < 4; ++nc)
#pragma unroll
      for (int q = 0; q < 4; ++q) {
        int code = col0 + nc * 16 + lh * 4 + q;
        float sc = es[nc][q] - sx2 * sev[nc][q] * (float)acc[nc][m][q];
        kins2(score_key(sc, code), k1, k2);
      }
#pragma unroll
    for (int s = 16; s <= 32; s <<= 1) {     // reduce over lh (4 lanes per lr)
      unsigned long long o1 = __shfl_xor(k1, s, 64);
      unsigned long long o2 = __shfl_xor(k2, s, 64);
      kins2(o1, k1, k2);
      kins2(o2, k1, k2);
    }
    if (lh == 0) {
      int gRow = mt * 256 + wr * 64 + m * 16 + lr;
      cand2[(size_t)gRow * 128 + ct * 4 + wc] = make_ulonglong2(k1, k2);
    }
  }
}

// ---- 4. global top-4 over 256 keys/row, exact f32 rescore, gather -----------
__global__ __launch_bounds__(256)
void vq_merge4(const float* __restrict__ x, const float* __restrict__ cb,
               const float* __restrict__ values, const float* __restrict__ e_sq,
               const ulonglong2* __restrict__ cand2, float* __restrict__ out) {
  int row = blockIdx.x * 4 + (threadIdx.x >> 6);
  int l = threadIdx.x & 63;

  unsigned long long k0 = KMAX, k1 = KMAX, k2 = KMAX, k3 = KMAX;
  const ulonglong2* base = cand2 + (size_t)row * 128;
#pragma unroll
  for (int u = 0; u < 2; ++u) {
    ulonglong2 e = base[l + 64 * u];
    kins4(e.x, k0, k1, k2, k3);
    kins4(e.y, k0, k1, k2, k3);
  }
#pragma unroll
  for (int s = 1; s < 64; s <<= 1) {
    unsigned long long o0 = __shfl_xor(k0, s, 64), o1 = __shfl_xor(k1, s, 64);
    unsigned long long o2 = __shfl_xor(k2, s, 64), o3 = __shfl_xor(k3, s, 64);
    kins4(o0, k0, k1, k2, k3); kins4(o1, k0, k1, k2, k3);
    kins4(o2, k0, k1, k2, k3); kins4(o3, k0, k1, k2, k3);
  }
  int i0 = (int)(k0 & 8191), i1 = (int)(k1 & 8191);
  int i2 = (int)(k2 & 8191), i3 = (int)(k3 & 8191);

  // exact f32 rescore (deterministic order)
  const float4* xr = (const float4*)(x + (size_t)row * D);
  const float4* c0 = (const float4*)(cb + (size_t)i0 * D);
  const float4* c1 = (const float4*)(cb + (size_t)i1 * D);
  const float4* c2 = (const float4*)(cb + (size_t)i2 * D);
  const float4* c3 = (const float4*)(cb + (size_t)i3 * D);
  float xsq = 0.f, t0 = 0.f, t1 = 0.f, t2 = 0.f, t3 = 0.f;
#pragma unroll
  for (int u = 0; u < 2; ++u) {
    float4 xv = xr[l + 64 * u];
    float4 a = c0[l + 64 * u], b = c1[l + 64 * u];
    float4 c = c2[l + 64 * u], e = c3[l + 64 * u];
    xsq += xv.x * xv.x + xv.y * xv.y + xv.z * xv.z + xv.w * xv.w;
    t0 += xv.x * a.x + xv.y * a.y + xv.z * a.z + xv.w * a.w;
    t1 += xv.x * b.x + xv.y * b.y + xv.z * b.z + xv.w * b.w;
    t2 += xv.x * c.x + xv.y * c.y + xv.z * c.z + xv.w * c.w;
    t3 += xv.x * e.x + xv.y * e.y + xv.z * e.z + xv.w * e.w;
  }
#pragma unroll
  for (int s = 1; s < 64; s <<= 1) {
    xsq += __shfl_xor(xsq, s, 64);
    t0 += __shfl_xor(t0, s, 64); t1 += __shfl_xor(t1, s, 64);
    t2 += __shfl_xor(t2, s, 64); t3 += __shfl_xor(t3, s, 64);
  }
  float D0 = xsq - 2.0f * t0 + e_sq[i0];
  float D1 = xsq - 2.0f * t1 + e_sq[i1];
  float D2 = xsq - 2.0f * t2 + e_sq[i2];
  float D3 = xsq - 2.0f * t3 + e_sq[i3];
  float bdist = D0; int best = i0;
  if (D1 < bdist || (D1 == bdist && i1 < best)) { bdist = D1; best = i1; }
  if (D2 < bdist || (D2 == bdist && i2 < best)) { bdist = D2; best = i2; }
  if (D3 < bdist || (D3 == bdist && i3 < best)) { bdist = D3; best = i3; }

  const float4* vsrc = (const float4*)(values + (size_t)best * D);
  float4* dst = (float4*)(out + (size_t)row * D);
  dst[l] = vsrc[l];
  dst[l + 64] = vsrc[l + 64];
}

// ============================================================================
extern "C" void kernel_launch(void* const* d_in, const int* in_sizes, int n_in,
                              void* d_out, int out_size, void* d_ws, size_t ws_size,
                              hipStream_t stream) {
  const float* x      = (const float*)d_in[0];
  const float* cb     = (const float*)d_in[1];
  const float* values = (const float*)d_in[2];
  float* out = (float*)d_out;

  const size_t A_BYTES = (size_t)M * D;               // 8 MB (i8)
  const size_t B_BYTES = (size_t)NCODE * D;           // 4 MB (i8)
  const size_t C_BYTES = (size_t)M * 128 * 16;        // 32 MB (key pairs)

  char* base = (char*)d_ws;
  char* Apack = base;
  char* Bpack = base + A_BYTES;
  ulonglong2* cand2 = (ulonglong2*)(base + A_BYTES + B_BYTES);
  float* qmul_x = (float*)(base + A_BYTES + B_BYTES + C_BYTES);
  float* sval_x = qmul_x + M;
  float* qmul_e = sval_x + M;
  float* sval_e = qmul_e + NCODE;
  float* e_sq   = sval_e + NCODE;

  const int LDS_GEMM = 131072;   // 2 x (32 KB A + 32 KB B)
  (void)hipFuncSetAttribute(reinterpret_cast<const void*>(vq_gemm_i8k),
                            hipFuncAttributeMaxDynamicSharedMemorySize, LDS_GEMM);

  scales_kernel<<<(M + NCODE) / 4, 256, 0, stream>>>(
      x, cb, qmul_x, sval_x, qmul_e, sval_e, e_sq);
  prep_i8<<<(M / 256) * 8, 256, 0, stream>>>(x, qmul_x, Apack);
  prep_i8<<<(NCODE / 256) * 8, 256, 0, stream>>>(cb, qmul_e, Bpack);
  vq_gemm_i8k<<<(M / 256) * (NCODE / 256), 1024, LDS_GEMM, stream>>>(
      Apack, Bpack, e_sq, sval_x, sval_e, cand2);
  vq_merge4<<<M / 4, 256, 0, stream>>>(x, cb, values, e_sq, cand2, out);
}

// Round 17
// 730.002 us; speedup vs baseline: 1.1062x; 1.1062x over previous
//
#include <hip/hip_runtime.h>
#include <hip/hip_bf16.h>

// VectorQuantize: argmin_k ||x - e_k||^2 then gather values[k].
// R17 = best-known composition + overhead trim.
//   GEMM: R13's vq_gemm_i8s verbatim (i8 128x128 BK=64, 4-wave blocks,
//         ~16 waves/CU, measured 571 us -- best of 13 structural variants).
//   Prep: FUSED scales+e_sq+quantize+transpose in ONE kernel (192 blocks x
//         1024 threads) -- removes the separate 80 MB scales pass and two
//         kernel launches. Packs are bit-identical to R13 (maxabs is
//         order-independent).
//   Rescue: per-wave top-2 sortable keys -> global top-4 -> exact f32
//         rescore (np tie semantics) -> gather values[best]. Unchanged.
//
// Ledger conclusion (R7-R16): GEMM wall 570-635 us across all precisions,
// staging mechanisms, barrier structures, occupancies, and maps; no pipe
// saturated -> environment's memory-latency x concurrency service limit.

#define D      512
#define M      16384
#define NCODE  8192
#define NSTEP  8           // K=512 / BK=64
#define TILEB  65536       // bytes per 128-row i8 tile (128*512)

typedef int   i32x4 __attribute__((ext_vector_type(4)));
typedef float f32x4 __attribute__((ext_vector_type(4)));

#define KMAX 0xFFFFFFFFFFFFFFFFull

__device__ __forceinline__ void gload16(const void* g, void* l) {
  __builtin_amdgcn_global_load_lds(
      (const __attribute__((address_space(1))) void*)g,
      (__attribute__((address_space(3))) void*)l, 16, 0, 0);
}

__device__ __forceinline__ unsigned long long score_key(float sc, int code) {
  unsigned int u = __float_as_uint(sc);
  unsigned int su = u ^ ((unsigned int)((int)u >> 31) | 0x80000000u);
  return ((unsigned long long)su << 32) | (unsigned int)code;
}

__device__ __forceinline__ void kins2(unsigned long long k,
                                      unsigned long long& k1, unsigned long long& k2) {
  if (k < k1) { k2 = k1; k1 = k; }
  else if (k < k2) { k2 = k; }
}

__device__ __forceinline__ void kins4(unsigned long long k,
    unsigned long long& k0, unsigned long long& k1,
    unsigned long long& k2, unsigned long long& k3) {
  if (k < k0)      { k3 = k2; k2 = k1; k1 = k0; k0 = k; }
  else if (k < k1) { k3 = k2; k2 = k1; k1 = k; }
  else if (k < k2) { k3 = k2; k2 = k; }
  else if (k < k3) { k3 = k; }
}

// ---- 1. FUSED: per-row scale + e_sq + i8 quantize + tile-transpose ----------
// Grid: 192 blocks (x tiles 0..127, cb tiles 128..191), 1024 threads.
// Pack layout (granule = 16 i8): P[tile128][k16 0..31][row 0..127][16].
__global__ __launch_bounds__(1024)
void prep_fused(const float* __restrict__ x, const float* __restrict__ cb,
                char* __restrict__ Apack, char* __restrict__ Bpack,
                float* __restrict__ sval_x, float* __restrict__ sval_e,
                float* __restrict__ e_sq) {
  __shared__ char  tile[128][144];   // 18 KB, 16B-aligned rows
  __shared__ float qmul_s[128];

  const int tid = threadIdx.x;
  const int t = blockIdx.x;
  const bool isx = t < 128;
  const int tl = isx ? t : t - 128;
  const float* src = (isx ? x : cb) + (size_t)tl * 128 * D;
  char* dst = (isx ? Apack : Bpack) + (size_t)tl * TILEB;

  // pass 1: row scales (8 threads per row, 64 floats each)
  {
    const int row = tid >> 3, part = tid & 7;
    const float4* p = (const float4*)(src + (size_t)row * D + part * 64);
    float ma = 0.f, ss = 0.f;
#pragma unroll
    for (int i = 0; i < 16; ++i) {
      float4 v = p[i];
      ma = fmaxf(ma, fmaxf(fmaxf(fabsf(v.x), fabsf(v.y)), fmaxf(fabsf(v.z), fabsf(v.w))));
      ss += v.x * v.x + v.y * v.y + v.z * v.z + v.w * v.w;
    }
#pragma unroll
    for (int s = 1; s < 8; s <<= 1) {      // 8 aligned lanes of one wave
      ma = fmaxf(ma, __shfl_xor(ma, s, 64));
      ss += __shfl_xor(ss, s, 64);
    }
    if (part == 0) {
      ma = fmaxf(ma, 1e-30f);
      qmul_s[row] = 127.0f / ma;
      const int grow = tl * 128 + row;
      if (isx) sval_x[grow] = ma / 127.0f;
      else { sval_e[grow] = ma / 127.0f; e_sq[grow] = ss; }
    }
  }
  __syncthreads();

  // pass 2: 4 chunks of 128 cols -> quantize + transpose (L2-hot re-read)
#pragma unroll 1
  for (int c = 0; c < 4; ++c) {
    {
      const int row = tid >> 3, k16l = tid & 7;     // 1024 granules
      const float4* p = (const float4*)(src + (size_t)row * D + c * 128 + k16l * 16);
      const float qm = qmul_s[row];
      union { i32x4 v; signed char b[16]; } pk;
#pragma unroll
      for (int u = 0; u < 4; ++u) {
        float4 v = p[u];
        float vv[4] = {v.x, v.y, v.z, v.w};
#pragma unroll
        for (int e = 0; e < 4; ++e) {
          int q = __float2int_rn(vv[e] * qm);
          q = q > 127 ? 127 : (q < -127 ? -127 : q);
          pk.b[u * 4 + e] = (signed char)q;
        }
      }
      *(i32x4*)&tile[row][k16l * 16] = pk.v;
    }
    __syncthreads();
    {
      const int row = tid & 127, k16l = tid >> 7;   // out granule
      i32x4 v = *(const i32x4*)&tile[row][k16l * 16];
      *(i32x4*)(dst + (((size_t)(c * 8 + k16l) * 128 + row) * 16)) = v;
    }
    __syncthreads();
  }
}

// ---- 2. 128x128-tile BK=64 i8 GEMM (R13 verbatim, 571 us) -------------------
// 256 threads = 4 waves (wr, wc in {0,1}). Wave tile: 64 rows x 64 codes.
// Swapped mfma_i32_16x16x64_i8(b, a): acc[nc][m][q] -> code = ct*128 + wc*64 +
// nc*16 + lh*4 + q, row = mt*128 + wr*64 + m*16 + lr.
__global__ __launch_bounds__(256, 4)
void vq_gemm_i8s(const char* __restrict__ Apack, const char* __restrict__ Bpack,
                 const float* __restrict__ e_sq,
                 const float* __restrict__ sval_x, const float* __restrict__ sval_e,
                 ulonglong2* __restrict__ cand2) {
  __shared__ char As[2][512 * 16];   // 2 x 8 KB
  __shared__ char Bs[2][512 * 16];   // 2 x 8 KB

  const int tid = threadIdx.x;
  const int w = tid >> 6, l = tid & 63;
  const int wr = w >> 1, wc = w & 1;
  const int lr = l & 15, lh = l >> 4;

  const int bid = blockIdx.x;
  const int xcd = bid & 7, idx = bid >> 3;   // 1024 blocks per XCD
  const int mt = xcd * 16 + (idx & 15);      // 128 m-tiles
  const int ct = idx >> 4;                   // 64 c-tiles

  const char* Abase = Apack + (size_t)mt * TILEB;
  const char* Bbase = Bpack + (size_t)ct * TILEB;

  i32x4 acc[4][4] = {};

#define STAGE(buf, t)                                                          \
  do {                                                                         \
    _Pragma("unroll")                                                          \
    for (int i = 0; i < 2; ++i) {                                              \
      const int g = tid + i * 256;                                             \
      gload16(Abase + ((size_t)(t) * 512 + g) * 16, As[(buf)] + (size_t)g * 16); \
      gload16(Bbase + ((size_t)(t) * 512 + g) * 16, Bs[(buf)] + (size_t)g * 16); \
    }                                                                          \
  } while (0)

#define COMPUTE(buf)                                                           \
  do {                                                                         \
    const i32x4* Ag = (const i32x4*)As[(buf)];                                 \
    const i32x4* Bg = (const i32x4*)Bs[(buf)];                                 \
    i32x4 a[4], b[4];                                                          \
    _Pragma("unroll")                                                          \
    for (int nc = 0; nc < 4; ++nc) b[nc] = Bg[lh * 128 + wc * 64 + nc * 16 + lr]; \
    _Pragma("unroll")                                                          \
    for (int m = 0; m < 4; ++m)   a[m] = Ag[lh * 128 + wr * 64 + m * 16 + lr];    \
    _Pragma("unroll")                                                          \
    for (int nc = 0; nc < 4; ++nc)                                             \
      _Pragma("unroll")                                                        \
      for (int m = 0; m < 4; ++m)                                              \
        acc[nc][m] = __builtin_amdgcn_mfma_i32_16x16x64_i8(b[nc], a[m],        \
                                                           acc[nc][m], 0, 0, 0); \
  } while (0)

  STAGE(0, 0);
  __syncthreads();
#pragma unroll 1
  for (int t = 0; t < NSTEP - 1; ++t) {
    const int cur = t & 1;
    STAGE(cur ^ 1, t + 1);       // prefetch issued before compute
    COMPUTE(cur);
    __syncthreads();             // one barrier per step
  }
  COMPUTE((NSTEP - 1) & 1);
#undef STAGE
#undef COMPUTE

  // ---- epilogue: per-row top-2 keys over this wave's 64-code strip ----
  const int col0 = ct * 128 + wc * 64;
  float es[4][4], sev[4][4], sxv[4];
#pragma unroll
  for (int nc = 0; nc < 4; ++nc) {
    float4 e4 = *(const float4*)&e_sq[col0 + nc * 16 + lh * 4];
    float4 s4 = *(const float4*)&sval_e[col0 + nc * 16 + lh * 4];
    es[nc][0] = e4.x; es[nc][1] = e4.y; es[nc][2] = e4.z; es[nc][3] = e4.w;
    sev[nc][0] = s4.x; sev[nc][1] = s4.y; sev[nc][2] = s4.z; sev[nc][3] = s4.w;
  }
#pragma unroll
  for (int m = 0; m < 4; ++m)
    sxv[m] = sval_x[mt * 128 + wr * 64 + m * 16 + lr];

#pragma unroll
  for (int m = 0; m < 4; ++m) {
    unsigned long long k1 = KMAX, k2 = KMAX;
    const float sx2 = 2.0f * sxv[m];
#pragma unroll
    for (int nc = 0; nc < 4; ++nc)
#pragma unroll
      for (int q = 0; q < 4; ++q) {
        int code = col0 + nc * 16 + lh * 4 + q;
        float sc = es[nc][q] - sx2 * sev[nc][q] * (float)acc[nc][m][q];
        kins2(score_key(sc, code), k1, k2);
      }
#pragma unroll
    for (int s = 16; s <= 32; s <<= 1) {     // reduce over lh (4 lanes per lr)
      unsigned long long o1 = __shfl_xor(k1, s, 64);
      unsigned long long o2 = __shfl_xor(k2, s, 64);
      kins2(o1, k1, k2);
      kins2(o2, k1, k2);
    }
    if (lh == 0) {
      int gRow = mt * 128 + wr * 64 + m * 16 + lr;
      cand2[(size_t)gRow * 128 + ct * 2 + wc] = make_ulonglong2(k1, k2);
    }
  }
}

// ---- 3. global top-4 over 256 keys/row, exact f32 rescore, gather -----------
__global__ __launch_bounds__(256)
void vq_merge4(const float* __restrict__ x, const float* __restrict__ cb,
               const float* __restrict__ values, const float* __restrict__ e_sq,
               const ulonglong2* __restrict__ cand2, float* __restrict__ out) {
  int row = blockIdx.x * 4 + (threadIdx.x >> 6);
  int l = threadIdx.x & 63;

  unsigned long long k0 = KMAX, k1 = KMAX, k2 = KMAX, k3 = KMAX;
  const ulonglong2* base = cand2 + (size_t)row * 128;
#pragma unroll
  for (int u = 0; u < 2; ++u) {
    ulonglong2 e = base[l + 64 * u];
    kins4(e.x, k0, k1, k2, k3);
    kins4(e.y, k0, k1, k2, k3);
  }
#pragma unroll
  for (int s = 1; s < 64; s <<= 1) {
    unsigned long long o0 = __shfl_xor(k0, s, 64), o1 = __shfl_xor(k1, s, 64);
    unsigned long long o2 = __shfl_xor(k2, s, 64), o3 = __shfl_xor(k3, s, 64);
    kins4(o0, k0, k1, k2, k3); kins4(o1, k0, k1, k2, k3);
    kins4(o2, k0, k1, k2, k3); kins4(o3, k0, k1, k2, k3);
  }
  int i0 = (int)(k0 & 8191), i1 = (int)(k1 & 8191);
  int i2 = (int)(k2 & 8191), i3 = (int)(k3 & 8191);

  // exact f32 rescore (deterministic order)
  const float4* xr = (const float4*)(x + (size_t)row * D);
  const float4* c0 = (const float4*)(cb + (size_t)i0 * D);
  const float4* c1 = (const float4*)(cb + (size_t)i1 * D);
  const float4* c2 = (const float4*)(cb + (size_t)i2 * D);
  const float4* c3 = (const float4*)(cb + (size_t)i3 * D);
  float xsq = 0.f, t0 = 0.f, t1 = 0.f, t2 = 0.f, t3 = 0.f;
#pragma unroll
  for (int u = 0; u < 2; ++u) {
    float4 xv = xr[l + 64 * u];
    float4 a = c0[l + 64 * u], b = c1[l + 64 * u];
    float4 c = c2[l + 64 * u], e = c3[l + 64 * u];
    xsq += xv.x * xv.x + xv.y * xv.y + xv.z * xv.z + xv.w * xv.w;
    t0 += xv.x * a.x + xv.y * a.y + xv.z * a.z + xv.w * a.w;
    t1 += xv.x * b.x + xv.y * b.y + xv.z * b.z + xv.w * b.w;
    t2 += xv.x * c.x + xv.y * c.y + xv.z * c.z + xv.w * c.w;
    t3 += xv.x * e.x + xv.y * e.y + xv.z * e.z + xv.w * e.w;
  }
#pragma unroll
  for (int s = 1; s < 64; s <<= 1) {
    xsq += __shfl_xor(xsq, s, 64);
    t0 += __shfl_xor(t0, s, 64); t1 += __shfl_xor(t1, s, 64);
    t2 += __shfl_xor(t2, s, 64); t3 += __shfl_xor(t3, s, 64);
  }
  float D0 = xsq - 2.0f * t0 + e_sq[i0];
  float D1 = xsq - 2.0f * t1 + e_sq[i1];
  float D2 = xsq - 2.0f * t2 + e_sq[i2];
  float D3 = xsq - 2.0f * t3 + e_sq[i3];
  float bdist = D0; int best = i0;
  if (D1 < bdist || (D1 == bdist && i1 < best)) { bdist = D1; best = i1; }
  if (D2 < bdist || (D2 == bdist && i2 < best)) { bdist = D2; best = i2; }
  if (D3 < bdist || (D3 == bdist && i3 < best)) { bdist = D3; best = i3; }

  const float4* vsrc = (const float4*)(values + (size_t)best * D);
  float4* dst = (float4*)(out + (size_t)row * D);
  dst[l] = vsrc[l];
  dst[l + 64] = vsrc[l + 64];
}

// ============================================================================
extern "C" void kernel_launch(void* const* d_in, const int* in_sizes, int n_in,
                              void* d_out, int out_size, void* d_ws, size_t ws_size,
                              hipStream_t stream) {
  const float* x      = (const float*)d_in[0];
  const float* cb     = (const float*)d_in[1];
  const float* values = (const float*)d_in[2];
  float* out = (float*)d_out;

  const size_t A_BYTES = (size_t)M * D;               // 8 MB (i8)
  const size_t B_BYTES = (size_t)NCODE * D;           // 4 MB (i8)
  const size_t C_BYTES = (size_t)M * 128 * 16;        // 32 MB (key pairs)

  char* base = (char*)d_ws;
  char* Apack = base;
  char* Bpack = base + A_BYTES;
  ulonglong2* cand2 = (ulonglong2*)(base + A_BYTES + B_BYTES);
  float* sval_x = (float*)(base + A_BYTES + B_BYTES + C_BYTES);
  float* sval_e = sval_x + M;
  float* e_sq   = sval_e + NCODE;

  prep_fused<<<M / 128 + NCODE / 128, 1024, 0, stream>>>(
      x, cb, Apack, Bpack, sval_x, sval_e, e_sq);
  vq_gemm_i8s<<<(M / 128) * (NCODE / 128), 256, 0, stream>>>(
      Apack, Bpack, e_sq, sval_x, sval_e, cand2);
  vq_merge4<<<M / 4, 256, 0, stream>>>(x, cb, values, e_sq, cand2, out);
}